// Round 14
// baseline (129.020 us; speedup 1.0000x reference)
//
#include <hip/hip_runtime.h>

#define NN 100000
#define NE 1600000
#define C 32

#define SHIFT 8
#define BINW 256                              // nodes per bin
#define NBIN ((NN + BINW - 1) / BINW)         // 391
#define EPB 8192                              // edges per chunk (binning)
#define NCHK ((NE + EPB - 1) / EPB)           // 196 chunks = k_bin blocks
#define SLACK 56                              // slots/(chunk,bin); lambda~21, 7.7 sigma
#define QPC 14                                // int4 quads per cell (SLACK/4)
#define CAPT (NCHK * SLACK)                   // 10976 tmp slots per bin
#define SCAP 5120                             // per-bin srt capacity (4096+16sigma)

__device__ __forceinline__ unsigned bf16rne(float f) {
    unsigned u = __float_as_uint(f);
    return (u + 0x7fffu + ((u >> 16) & 1u)) >> 16;
}
__device__ __forceinline__ float blo(unsigned u) { return __uint_as_float(u << 16); }
__device__ __forceinline__ float bhi(unsigned u) { return __uint_as_float(u & 0xffff0000u); }

// ---------------- kernels ----------------

// single-pass scatter into chunk-partitioned bins (R11's proven shape).
__global__ __launch_bounds__(1024) void k_bin(const int* __restrict__ ei,
                                              int* __restrict__ tmp,
                                              int* __restrict__ cfill) {
    __shared__ int lcur[NBIN];
    int b = blockIdx.x, t = threadIdx.x;
    if (t < NBIN) lcur[t] = t * CAPT + b * SLACK;
    __syncthreads();
    int e0 = b * EPB, e1 = min(e0 + EPB, NE);   // windows %4 == 0
    const int4* src4 = (const int4*)ei;
    const int4* col4 = (const int4*)(ei + NE);
    for (int q = (e0 >> 2) + t; q < (e1 >> 2); q += 1024) {
        int4 s = src4[q];
        int4 c = col4[q];
        int p0 = atomicAdd(&lcur[c.x >> SHIFT], 1);
        tmp[p0] = (s.x << SHIFT) | (c.x & (BINW - 1));
        int p1 = atomicAdd(&lcur[c.y >> SHIFT], 1);
        tmp[p1] = (s.y << SHIFT) | (c.y & (BINW - 1));
        int p2 = atomicAdd(&lcur[c.z >> SHIFT], 1);
        tmp[p2] = (s.z << SHIFT) | (c.z & (BINW - 1));
        int p3 = atomicAdd(&lcur[c.w >> SHIFT], 1);
        tmp[p3] = (s.w << SHIFT) | (c.w & (BINW - 1));
    }
    __syncthreads();
    if (t < NBIN)                               // [b][i]: coalesced write
        cfill[b * NBIN + t] = lcur[t] - (t * CAPT + b * SLACK);
}

// fused degree + place + linear: one block per bin. The place walk re-reads
// the exact lines the hist walk just fetched (same block, same XCD — L2-hot;
// R12 proved cross-kernel re-walks get no such reuse) and emits a compact
// per-bin srt (sequential-ish writes) + off[node] = loc | deg<<16.
__global__ __launch_bounds__(1024) void k_degLinPlace(const int* __restrict__ cfill,
                                                      const int* __restrict__ tmp,
                                                      const float* __restrict__ x,
                                                      const float* __restrict__ W,
                                                      int* __restrict__ srt,
                                                      int* __restrict__ off,
                                                      unsigned* __restrict__ hu) {
    __shared__ int ccnt[NCHK];
    __shared__ int cnt[BINW];
    __shared__ int lcur[BINW];
    __shared__ int wtot[4], wbase[4];
    __shared__ float Ws[C][C + 1];
    __shared__ float xs[BINW][C];              // 32KB; total LDS ~40KB
    int bin = blockIdx.x, t = threadIdx.x;
    if (t < NCHK) ccnt[t] = cfill[t * NBIN + bin];
    if (t < BINW) cnt[t] = 0;
    Ws[t >> 5][t & 31] = W[t];                 // C*C == 1024 exactly
    for (int i = t; i < BINW * C; i += 1024) {
        int idx = (bin << SHIFT) * C + i;      // coalesced 32KB x-rows
        xs[i >> 5][i & 31] = (idx < NN * C) ? x[idx] : 0.0f;
    }
    __syncthreads();
    const int4* tp4 = (const int4*)tmp + bin * (CAPT >> 2);
    for (int q = t; q < (CAPT >> 2); q += 1024) {      // hist walk (quad-skip)
        int chunk = q / QPC;                   // magic-mul division
        int o = (q - chunk * QPC) << 2;
        int fill = ccnt[chunk];
        if (o < fill) {
            int4 v = tp4[q];
            atomicAdd(&cnt[v.x & (BINW - 1)], 1);
            if (o + 1 < fill) atomicAdd(&cnt[v.y & (BINW - 1)], 1);
            if (o + 2 < fill) atomicAdd(&cnt[v.z & (BINW - 1)], 1);
            if (o + 3 < fill) atomicAdd(&cnt[v.w & (BINW - 1)], 1);
        }
    }
    __syncthreads();
    // exclusive scan of 256 counts (threads 0..255 = waves 0..3)
    int lane = t & 63, w4 = t >> 6;
    int cv = 0, v = 0;
    if (t < BINW) {
        cv = cnt[t];
        v = cv;
#pragma unroll
        for (int d = 1; d < 64; d <<= 1) {
            int u = __shfl_up(v, d);
            if (lane >= d) v += u;
        }
        if (lane == 63) wtot[w4] = v;
    }
    __syncthreads();
    if (t == 0) {
        int r = 0;
#pragma unroll
        for (int k = 0; k < 4; ++k) { wbase[k] = r; r += wtot[k]; }
    }
    __syncthreads();
    if (t < BINW) {
        int loc = wbase[w4] + v - cv;
        lcur[t] = loc;
        int node = (bin << SHIFT) + t;
        if (node < NN) off[node] = loc | (cv << 16);   // loc<5120, deg<65536
    }
    __syncthreads();
    int sbase = bin * SCAP;
    for (int q = t; q < (CAPT >> 2); q += 1024) {      // place walk (L2-hot)
        int chunk = q / QPC;
        int o = (q - chunk * QPC) << 2;
        int fill = ccnt[chunk];
        if (o < fill) {
            int4 e = tp4[q];
            srt[sbase + atomicAdd(&lcur[e.x & (BINW - 1)], 1)] = e.x >> SHIFT;
            if (o + 1 < fill) srt[sbase + atomicAdd(&lcur[e.y & (BINW - 1)], 1)] = e.y >> SHIFT;
            if (o + 2 < fill) srt[sbase + atomicAdd(&lcur[e.z & (BINW - 1)], 1)] = e.z >> SHIFT;
            if (o + 3 < fill) srt[sbase + atomicAdd(&lcur[e.w & (BINW - 1)], 1)] = e.w >> SHIFT;
        }
    }
    // linear: hu = bf16(rsqrt(1+deg) * xW^T)  (cnt still live in LDS)
    int m = t & 15, nl0 = t >> 4;              // 64 node-slots x 16 ch-pairs
#pragma unroll
    for (int rep = 0; rep < 4; ++rep) {
        int nl = nl0 + (rep << 6);
        int node = (bin << SHIFT) + nl;
        if (node < NN) {
            float a0 = 0.0f, a1 = 0.0f;
#pragma unroll
            for (int k = 0; k < C; ++k) {
                float xv = xs[nl][k];
                a0 += xv * Ws[2 * m][k];
                a1 += xv * Ws[2 * m + 1][k];
            }
            float d = rsqrtf(1.0f + (float)cnt[nl]);   // incl. self-loop
            hu[node * 16 + m] = bf16rne(a0 * d) | (bf16rne(a1 * d) << 16);
        }
    }
}

// pure gather, grid decoupled from bins: 64 nodes/block x 1563 blocks.
// srt read is contiguous per node run (no gapped walk, no validity logic);
// 4-lane group x uint4 = 16 edge rows per wave-instruction.
__global__ __launch_bounds__(256) void k_agg(const int* __restrict__ off,
                                             const int* __restrict__ srt,
                                             const uint4* __restrict__ hu4,
                                             const float* __restrict__ b,
                                             float* __restrict__ out) {
    int t = threadIdx.x;
    int g = t >> 2, m = t & 3;                 // 64 groups x 4 lanes
    int node = blockIdx.x * 64 + g;
    if (node >= NN) return;
    int ov = off[node];
    int beg = (node >> SHIFT) * SCAP + (ov & 0xffff);
    int cnt = ov >> 16;
    float s0 = 0.0f, s1 = 0.0f, s2 = 0.0f, s3 = 0.0f;
    float s4 = 0.0f, s5 = 0.0f, s6 = 0.0f, s7 = 0.0f;
    int j = beg, jend = beg + cnt;
    for (; j + 3 < jend; j += 4) {             // 4 rows in flight per lane
        int r0 = srt[j], r1 = srt[j + 1], r2 = srt[j + 2], r3 = srt[j + 3];
        uint4 u0 = hu4[r0 * 4 + m];
        uint4 u1 = hu4[r1 * 4 + m];
        uint4 u2 = hu4[r2 * 4 + m];
        uint4 u3 = hu4[r3 * 4 + m];
        s0 += blo(u0.x); s1 += bhi(u0.x); s2 += blo(u0.y); s3 += bhi(u0.y);
        s4 += blo(u0.z); s5 += bhi(u0.z); s6 += blo(u0.w); s7 += bhi(u0.w);
        s0 += blo(u1.x); s1 += bhi(u1.x); s2 += blo(u1.y); s3 += bhi(u1.y);
        s4 += blo(u1.z); s5 += bhi(u1.z); s6 += blo(u1.w); s7 += bhi(u1.w);
        s0 += blo(u2.x); s1 += bhi(u2.x); s2 += blo(u2.y); s3 += bhi(u2.y);
        s4 += blo(u2.z); s5 += bhi(u2.z); s6 += blo(u2.w); s7 += bhi(u2.w);
        s0 += blo(u3.x); s1 += bhi(u3.x); s2 += blo(u3.y); s3 += bhi(u3.y);
        s4 += blo(u3.z); s5 += bhi(u3.z); s6 += blo(u3.w); s7 += bhi(u3.w);
    }
    for (; j < jend; ++j) {
        uint4 u = hu4[srt[j] * 4 + m];
        s0 += blo(u.x); s1 += bhi(u.x); s2 += blo(u.y); s3 += bhi(u.y);
        s4 += blo(u.z); s5 += bhi(u.z); s6 += blo(u.w); s7 += bhi(u.w);
    }
    float dn = rsqrtf(1.0f + (float)cnt);
    uint4 us = hu4[node * 4 + m];              // self-loop row (pre-scaled)
    float4 b0 = ((const float4*)b)[2 * m];
    float4 b1 = ((const float4*)b)[2 * m + 1];
    float4 o0, o1;
    o0.x = b0.x + dn * (s0 + blo(us.x));
    o0.y = b0.y + dn * (s1 + bhi(us.x));
    o0.z = b0.z + dn * (s2 + blo(us.y));
    o0.w = b0.w + dn * (s3 + bhi(us.y));
    o1.x = b1.x + dn * (s4 + blo(us.z));
    o1.y = b1.y + dn * (s5 + bhi(us.z));
    o1.z = b1.z + dn * (s6 + blo(us.w));
    o1.w = b1.w + dn * (s7 + bhi(us.w));
    ((float4*)out)[node * 8 + 2 * m] = o0;
    ((float4*)out)[node * 8 + 2 * m + 1] = o1;
}

// ---------------- launch ----------------

extern "C" void kernel_launch(void* const* d_in, const int* in_sizes, int n_in,
                              void* d_out, int out_size, void* d_ws, size_t ws_size,
                              hipStream_t stream) {
    const float* x  = (const float*)d_in[0];
    const int*   ei = (const int*)d_in[1];
    const float* W  = (const float*)d_in[2];
    const float* b  = (const float*)d_in[3];
    float* out = (float*)d_out;

    // ws (~33 MB of 256 MB pool) — no overlays, all buffers distinct
    char* ws = (char*)d_ws;
    size_t o = 0;
    int*      tmp   = (int*)(ws + o);      o += (size_t)NBIN * CAPT * 4;   o = (o + 255) & ~(size_t)255;
    int*      srt   = (int*)(ws + o);      o += (size_t)NBIN * SCAP * 4;   o = (o + 255) & ~(size_t)255;
    unsigned* hu    = (unsigned*)(ws + o); o += (size_t)NN * 16 * 4;       o = (o + 255) & ~(size_t)255;
    int*      cfill = (int*)(ws + o);      o += (size_t)NCHK * NBIN * 4;   o = (o + 255) & ~(size_t)255;
    int*      off   = (int*)(ws + o);

    k_bin<<<NCHK, 1024, 0, stream>>>(ei, tmp, cfill);
    k_degLinPlace<<<NBIN, 1024, 0, stream>>>(cfill, tmp, x, W, srt, off, hu);
    k_agg<<<(NN + 63) / 64, 256, 0, stream>>>(off, srt, (const uint4*)hu, b, out);
}

// Round 15
// 119.922 us; speedup vs baseline: 1.0759x; 1.0759x over previous
//
#include <hip/hip_runtime.h>

#define NN 100000
#define NE 1600000
#define C 32

#define SHIFT 8
#define BINW 256                              // nodes per bin
#define NBIN ((NN + BINW - 1) / BINW)         // 391
#define EPB 8192                              // edges per chunk (binning)
#define NCHK ((NE + EPB - 1) / EPB)           // 196 chunks = bin-role blocks
#define SLACK 56                              // slots/(chunk,bin); lambda~21, 7.7 sigma
#define QPC 14                                // int4 quads per cell (SLACK/4)
#define CAPT (NCHK * SLACK)                   // 10976 tmp slots per bin
#define SCAP 5120                             // LDS sorted-list cap (4096+16sigma)
#define NLIN ((NN + 63) / 64)                 // 1563 linear-role blocks (64 nodes each)

__device__ __forceinline__ unsigned bf16rne(float f) {
    unsigned u = __float_as_uint(f);
    return (u + 0x7fffu + ((u >> 16) & 1u)) >> 16;
}
__device__ __forceinline__ float blo(unsigned u) { return __uint_as_float(u << 16); }
__device__ __forceinline__ float bhi(unsigned u) { return __uint_as_float(u & 0xffff0000u); }

// ---------------- kernels ----------------

// hetero-grid K1: blocks [0,196) scatter edges into chunk-partitioned bins
// (R11's proven k_bin body); blocks [196,1759) compute UNSCALED
// hu = bf16(x @ W^T). Linear no longer waits on binning (the dinv prescale
// moved to K2) — its compute-dense waves co-reside with bin's latency-bound
// waves (breadth-first dispatch: 196 bin blocks land 1/CU, linear fills in).
__global__ __launch_bounds__(1024) void k_binLin(const int* __restrict__ ei,
                                                 const float* __restrict__ x,
                                                 const float* __restrict__ W,
                                                 int* __restrict__ tmp,
                                                 int* __restrict__ cfill,
                                                 unsigned* __restrict__ hu) {
    __shared__ int lcur[NBIN];
    __shared__ float Ws[C][C + 1];
    __shared__ float xs[64][C];
    int b = blockIdx.x, t = threadIdx.x;
    if (b < NCHK) {
        // ---- bin role ----
        if (t < NBIN) lcur[t] = t * CAPT + b * SLACK;
        __syncthreads();
        int e0 = b * EPB, e1 = min(e0 + EPB, NE);   // windows %4 == 0
        const int4* src4 = (const int4*)ei;
        const int4* col4 = (const int4*)(ei + NE);
        for (int q = (e0 >> 2) + t; q < (e1 >> 2); q += 1024) {
            int4 s = src4[q];
            int4 c = col4[q];
            int p0 = atomicAdd(&lcur[c.x >> SHIFT], 1);
            tmp[p0] = (s.x << SHIFT) | (c.x & (BINW - 1));
            int p1 = atomicAdd(&lcur[c.y >> SHIFT], 1);
            tmp[p1] = (s.y << SHIFT) | (c.y & (BINW - 1));
            int p2 = atomicAdd(&lcur[c.z >> SHIFT], 1);
            tmp[p2] = (s.z << SHIFT) | (c.z & (BINW - 1));
            int p3 = atomicAdd(&lcur[c.w >> SHIFT], 1);
            tmp[p3] = (s.w << SHIFT) | (c.w & (BINW - 1));
        }
        __syncthreads();
        if (t < NBIN)                           // [b][i]: coalesced write
            cfill[b * NBIN + t] = lcur[t] - (t * CAPT + b * SLACK);
    } else {
        // ---- linear role: 64 nodes, UNSCALED ----
        int node0 = (b - NCHK) * 64;
        Ws[t >> 5][t & 31] = W[t];              // C*C == 1024 exactly
        for (int i = t; i < 64 * C; i += 1024) {
            int idx = node0 * C + i;            // coalesced 8KB x-rows
            xs[i >> 5][i & 31] = (idx < NN * C) ? x[idx] : 0.0f;
        }
        __syncthreads();
        int m = t & 15, nl = t >> 4;            // 64 slots x 16 ch-pairs
        int node = node0 + nl;
        if (node < NN) {
            float a0 = 0.0f, a1 = 0.0f;
#pragma unroll
            for (int k = 0; k < C; ++k) {
                float xv = xs[nl][k];
                a0 += xv * Ws[2 * m][k];
                a1 += xv * Ws[2 * m + 1][k];
            }
            hu[node * 16 + m] = bf16rne(a0) | (bf16rne(a1) << 16);
        }
    }
}

// K2: per-bin degree hist (quad-skip walk of the gapped segment) -> deg
// write (for K3's scan) + in-place dinv rescale of the bin's own 256 hu
// rows (16KB coalesced RMW; each block owns its rows exclusively).
__global__ __launch_bounds__(1024) void k_degScale(const int* __restrict__ cfill,
                                                   const int* __restrict__ tmp,
                                                   int* __restrict__ deg,
                                                   unsigned* __restrict__ hu) {
    __shared__ int ccnt[NCHK];
    __shared__ int cnt[BINW];
    __shared__ float di[BINW];
    int bin = blockIdx.x, t = threadIdx.x;
    if (t < NCHK) ccnt[t] = cfill[t * NBIN + bin];
    if (t < BINW) cnt[t] = 0;
    __syncthreads();
    const int4* tp4 = (const int4*)tmp + bin * (CAPT >> 2);
    for (int q = t; q < (CAPT >> 2); q += 1024) {
        int chunk = q / QPC;                    // magic-mul division
        int o = (q - chunk * QPC) << 2;
        int fill = ccnt[chunk];
        if (o < fill) {                         // skip empty quads pre-load
            int4 v = tp4[q];
            atomicAdd(&cnt[v.x & (BINW - 1)], 1);
            if (o + 1 < fill) atomicAdd(&cnt[v.y & (BINW - 1)], 1);
            if (o + 2 < fill) atomicAdd(&cnt[v.z & (BINW - 1)], 1);
            if (o + 3 < fill) atomicAdd(&cnt[v.w & (BINW - 1)], 1);
        }
    }
    __syncthreads();
    if (t < BINW) {
        int cv = cnt[t];
        di[t] = rsqrtf(1.0f + (float)cv);       // deg incl. self-loop
        int node = (bin << SHIFT) + t;
        if (node < NN) deg[node] = cv;
    }
    __syncthreads();
    // scale own rows: 4096 uints / 1024 thr = 4 each, fully coalesced
    unsigned* hb = hu + (size_t)(bin << SHIFT) * 16;
    int lim = (min(NN - (bin << SHIFT), BINW)) * 16;
    for (int i = t; i < lim; i += 1024) {
        unsigned u = hb[i];
        float d = di[i >> 4];
        hb[i] = bf16rne(blo(u) * d) | (bf16rne(bhi(u) * d) << 16);
    }
}

// K3: fused place+aggregate — R11's proven kernel, verbatim.
#define AGG_T 1024
__global__ __launch_bounds__(AGG_T) void k_placeAgg(const int* __restrict__ cfill,
                                                    const int* __restrict__ tmp,
                                                    const int* __restrict__ deg,
                                                    const uint4* __restrict__ hu4,
                                                    const float* __restrict__ b,
                                                    float* __restrict__ out) {
    __shared__ int ccnt[NCHK];
    __shared__ int dg[BINW];
    __shared__ int lbase[BINW];
    __shared__ int lcur[BINW];
    __shared__ int lsort[SCAP];               // ~20.5KB; total LDS ~24.5KB
    __shared__ int wtot[4], wbase[4];
    int bin = blockIdx.x, t = threadIdx.x;
    if (t < NCHK) ccnt[t] = cfill[t * NBIN + bin];
    if (t < BINW) {
        int node = (bin << SHIFT) + t;
        dg[t] = (node < NN) ? deg[node] : 0;   // coalesced, L2-hot
    }
    __syncthreads();
    int lane = t & 63, w4 = t >> 6;
    int cv = 0, v = 0;
    if (t < BINW) {
        cv = dg[t];
        v = cv;
#pragma unroll
        for (int d = 1; d < 64; d <<= 1) {
            int u = __shfl_up(v, d);
            if (lane >= d) v += u;
        }
        if (lane == 63) wtot[w4] = v;
    }
    __syncthreads();
    if (t == 0) {
        int r = 0;
#pragma unroll
        for (int k = 0; k < 4; ++k) { wbase[k] = r; r += wtot[k]; }
    }
    __syncthreads();
    if (t < BINW) {
        int loc = wbase[w4] + v - cv;          // exclusive local offset
        lbase[t] = loc;
        lcur[t] = loc;
    }
    __syncthreads();
    const int4* tp4 = (const int4*)tmp + bin * (CAPT >> 2);
    for (int q = t; q < (CAPT >> 2); q += AGG_T) {
        int chunk = q / QPC;
        int off = (q - chunk * QPC) << 2;
        int fill = ccnt[chunk];
        if (off < fill) {
            int4 e = tp4[q];
            lsort[atomicAdd(&lcur[e.x & (BINW - 1)], 1)] = e.x >> SHIFT;
            if (off + 1 < fill) lsort[atomicAdd(&lcur[e.y & (BINW - 1)], 1)] = e.y >> SHIFT;
            if (off + 2 < fill) lsort[atomicAdd(&lcur[e.z & (BINW - 1)], 1)] = e.z >> SHIFT;
            if (off + 3 < fill) lsort[atomicAdd(&lcur[e.w & (BINW - 1)], 1)] = e.w >> SHIFT;
        }
    }
    __syncthreads();
    // gather: 4-lane group per node; lane m covers channels 8m..8m+7
    int g = t >> 2, m = t & 3;
    int beg = lbase[g], cnt = dg[g];
    float s0 = 0.0f, s1 = 0.0f, s2 = 0.0f, s3 = 0.0f;
    float s4 = 0.0f, s5 = 0.0f, s6 = 0.0f, s7 = 0.0f;
    int j = beg, jend = beg + cnt;
    for (; j + 3 < jend; j += 4) {             // 4 rows in flight per lane
        int r0 = lsort[j], r1 = lsort[j + 1], r2 = lsort[j + 2], r3 = lsort[j + 3];
        uint4 u0 = hu4[r0 * 4 + m];
        uint4 u1 = hu4[r1 * 4 + m];
        uint4 u2 = hu4[r2 * 4 + m];
        uint4 u3 = hu4[r3 * 4 + m];
        s0 += blo(u0.x); s1 += bhi(u0.x); s2 += blo(u0.y); s3 += bhi(u0.y);
        s4 += blo(u0.z); s5 += bhi(u0.z); s6 += blo(u0.w); s7 += bhi(u0.w);
        s0 += blo(u1.x); s1 += bhi(u1.x); s2 += blo(u1.y); s3 += bhi(u1.y);
        s4 += blo(u1.z); s5 += bhi(u1.z); s6 += blo(u1.w); s7 += bhi(u1.w);
        s0 += blo(u2.x); s1 += bhi(u2.x); s2 += blo(u2.y); s3 += bhi(u2.y);
        s4 += blo(u2.z); s5 += bhi(u2.z); s6 += blo(u2.w); s7 += bhi(u2.w);
        s0 += blo(u3.x); s1 += bhi(u3.x); s2 += blo(u3.y); s3 += bhi(u3.y);
        s4 += blo(u3.z); s5 += bhi(u3.z); s6 += blo(u3.w); s7 += bhi(u3.w);
    }
    for (; j < jend; ++j) {
        uint4 u = hu4[lsort[j] * 4 + m];
        s0 += blo(u.x); s1 += bhi(u.x); s2 += blo(u.y); s3 += bhi(u.y);
        s4 += blo(u.z); s5 += bhi(u.z); s6 += blo(u.w); s7 += bhi(u.w);
    }
    int node = (bin << SHIFT) + g;
    if (node < NN) {
        float dn = rsqrtf(1.0f + (float)cnt);
        uint4 us = hu4[node * 4 + m];          // self-loop row (pre-scaled)
        float4 b0 = ((const float4*)b)[2 * m];
        float4 b1 = ((const float4*)b)[2 * m + 1];
        float4 o0, o1;
        o0.x = b0.x + dn * (s0 + blo(us.x));
        o0.y = b0.y + dn * (s1 + bhi(us.x));
        o0.z = b0.z + dn * (s2 + blo(us.y));
        o0.w = b0.w + dn * (s3 + bhi(us.y));
        o1.x = b1.x + dn * (s4 + blo(us.z));
        o1.y = b1.y + dn * (s5 + bhi(us.z));
        o1.z = b1.z + dn * (s6 + blo(us.w));
        o1.w = b1.w + dn * (s7 + bhi(us.w));
        ((float4*)out)[node * 8 + 2 * m] = o0;
        ((float4*)out)[node * 8 + 2 * m + 1] = o1;
    }
}

// ---------------- launch ----------------

extern "C" void kernel_launch(void* const* d_in, const int* in_sizes, int n_in,
                              void* d_out, int out_size, void* d_ws, size_t ws_size,
                              hipStream_t stream) {
    const float* x  = (const float*)d_in[0];
    const int*   ei = (const int*)d_in[1];
    const float* W  = (const float*)d_in[2];
    const float* b  = (const float*)d_in[3];
    float* out = (float*)d_out;

    // ws (~25 MB of 256 MB pool) — no overlays, all buffers distinct
    char* ws = (char*)d_ws;
    size_t o = 0;
    int*      tmp   = (int*)(ws + o);      o += (size_t)NBIN * CAPT * 4;   o = (o + 255) & ~(size_t)255;
    unsigned* hu    = (unsigned*)(ws + o); o += (size_t)NN * 16 * 4;       o = (o + 255) & ~(size_t)255;
    int*      cfill = (int*)(ws + o);      o += (size_t)NCHK * NBIN * 4;   o = (o + 255) & ~(size_t)255;
    int*      deg   = (int*)(ws + o);

    k_binLin<<<NCHK + NLIN, 1024, 0, stream>>>(ei, x, W, tmp, cfill, hu);
    k_degScale<<<NBIN, 1024, 0, stream>>>(cfill, tmp, deg, hu);
    k_placeAgg<<<NBIN, AGG_T, 0, stream>>>(cfill, tmp, deg, (const uint4*)hu, b, out);
}